// Round 1
// baseline (444.105 us; speedup 1.0000x reference)
//
#include <hip/hip_runtime.h>

// y[0,:]   = x[0,:]
// y[i,:]   = x[i,:] + x[i-1,:]*w[i-1] + b[i-1]   (i = 1..H-1)
//
// Memory-bound: 256 MiB in + 256 MiB out fp32. Register-carry over rows so
// each x row is read once from HBM (vs twice for the naive per-element form).

#define H_DIM 8192
#define D_DIM 8192
#define D4 (D_DIM / 4)          // 2048 float4 per row
#define ROWS_PER_CHUNK 32       // grid.y = H/ROWS_PER_CHUNK = 256
#define BLOCK 256               // grid.x = D4/BLOCK = 8

__global__ __launch_bounds__(BLOCK) void lateral_kernel(
    const float4* __restrict__ x,
    const float* __restrict__ w,
    const float* __restrict__ b,
    float4* __restrict__ y) {

    const int col = blockIdx.x * BLOCK + threadIdx.x;   // float4 column index
    const int r0  = blockIdx.y * ROWS_PER_CHUNK;

    float4 prev;
    int rstart;
    if (r0 == 0) {
        // first chunk: row 0 is a pass-through copy
        float4 cur = x[col];
        y[col] = cur;
        prev = cur;
        rstart = 1;
    } else {
        prev = x[(size_t)(r0 - 1) * D4 + col];
        rstart = r0;
    }

    const int rend = r0 + ROWS_PER_CHUNK;
    #pragma unroll 4
    for (int i = rstart; i < rend; ++i) {
        float4 cur = x[(size_t)i * D4 + col];
        // wave-uniform scalar loads (i is uniform within the block)
        float wi = w[i - 1];
        float bi = b[i - 1];
        float4 o;
        o.x = fmaf(prev.x, wi, cur.x + bi);
        o.y = fmaf(prev.y, wi, cur.y + bi);
        o.z = fmaf(prev.z, wi, cur.z + bi);
        o.w = fmaf(prev.w, wi, cur.w + bi);
        y[(size_t)i * D4 + col] = o;
        prev = cur;
    }
}

extern "C" void kernel_launch(void* const* d_in, const int* in_sizes, int n_in,
                              void* d_out, int out_size, void* d_ws, size_t ws_size,
                              hipStream_t stream) {
    const float4* x = (const float4*)d_in[0];
    const float*  w = (const float*)d_in[1];
    const float*  b = (const float*)d_in[2];
    float4* y = (float4*)d_out;

    dim3 grid(D4 / BLOCK, H_DIM / ROWS_PER_CHUNK);
    dim3 block(BLOCK);
    lateral_kernel<<<grid, block, 0, stream>>>(x, w, b, y);
}

// Round 2
// 425.324 us; speedup vs baseline: 1.0442x; 1.0442x over previous
//
#include <hip/hip_runtime.h>

// y[0,:] = x[0,:]
// y[i,:] = x[i,:] + x[i-1,:]*w[i-1] + b[i-1]   (i = 1..H-1)
//
// Pure elementwise, copy-kernel-shaped for max memory-level parallelism:
// no loop-carried registers, one float4 per thread, 2 independent loads.
// The x[idx-D4] re-read is issued ~concurrently with neighbor rows' primary
// reads, so the 256 MiB L3 absorbs most of it. Nontemporal stores keep the
// write stream from evicting x lines out of L2/L3.

#define H_DIM 8192
#define D_DIM 8192
#define D4 (D_DIM / 4)            // 2048 float4 per row (power of two)
#define N4 (H_DIM * D4)           // 16,777,216 float4 total
#define BLOCK 256

typedef float v4f __attribute__((ext_vector_type(4)));

__global__ __launch_bounds__(BLOCK, 8) void lateral_kernel(
    const v4f* __restrict__ x,
    const float* __restrict__ w,
    const float* __restrict__ b,
    v4f* __restrict__ y) {

    const int idx = blockIdx.x * BLOCK + threadIdx.x;   // float4 index

    v4f cur = x[idx];
    v4f o;
    if (idx >= D4) {
        // row = idx / D4 ; wave-uniform (64-lane waves are aligned within rows)
        const int row = idx >> 11;
        v4f pv = x[idx - D4];          // independent load, issues in parallel
        const float wi = w[row - 1];
        const float bi = b[row - 1];
        o.x = fmaf(pv.x, wi, cur.x + bi);
        o.y = fmaf(pv.y, wi, cur.y + bi);
        o.z = fmaf(pv.z, wi, cur.z + bi);
        o.w = fmaf(pv.w, wi, cur.w + bi);
    } else {
        o = cur;                        // row 0 pass-through
    }
    __builtin_nontemporal_store(o, &y[idx]);
}

extern "C" void kernel_launch(void* const* d_in, const int* in_sizes, int n_in,
                              void* d_out, int out_size, void* d_ws, size_t ws_size,
                              hipStream_t stream) {
    const v4f*   x = (const v4f*)d_in[0];
    const float* w = (const float*)d_in[1];
    const float* b = (const float*)d_in[2];
    v4f* y = (v4f*)d_out;

    lateral_kernel<<<N4 / BLOCK, BLOCK, 0, stream>>>(x, w, b, y);
}